// Round 3
// baseline (440.830 us; speedup 1.0000x reference)
//
#include <hip/hip_runtime.h>
#include <cstdint>
#include <cstddef>

#define N_NODES 8192
#define IN_DIM  256
#define OUT_DIM 64
#define HEADS   2
#define FEAT    128           // OUT_DIM*HEADS
#define NTILES  9             // 144 B-cols: 128 feat + 2 denom + 14 pad
#define ACC_STRIDE 132
#define KSPLIT  8

typedef __bf16 bf16x8 __attribute__((ext_vector_type(8)));
typedef float  f32x4  __attribute__((ext_vector_type(4)));
typedef int    i32x4  __attribute__((ext_vector_type(4)));
typedef unsigned uu32x4 __attribute__((ext_vector_type(4)));

static __device__ __forceinline__ unsigned short f2bf(float f) {
  unsigned u = __float_as_uint(f);
  u += 0x7FFFu + ((u >> 16) & 1u);     // round-to-nearest-even
  return (unsigned short)(u >> 16);
}

// ---------------------------------------------------------------- k_vr
// vr[h][k] = sum_d attn_r[h][d] * W[h*64+d][k]   (2x256)
__global__ void k_vr(const float* __restrict__ W, const float* __restrict__ attn_r,
                     float* __restrict__ vr) {
  const int t = threadIdx.x;               // 512 threads
  const int h = t >> 8, k = t & 255;
  float s = 0.f;
  for (int d = 0; d < OUT_DIM; d++)
    s += attn_r[h*OUT_DIM + d] * W[(size_t)(h*OUT_DIM + d)*IN_DIM + k];
  vr[h*IN_DIM + k] = s;
}

// ---------------------------------------------------------------- k_h
// H = x @ W^T  (fp32, 8192x128). 256 blocks: 64-row x 64-col tiles.
// float4 LDS reads ([row][k] layout, stride 68 => 2-way-max bank aliasing, free)
__global__ __launch_bounds__(256) void k_h(const float* __restrict__ x,
                                           const float* __restrict__ W,
                                           float* __restrict__ H) {
  const int rb = blockIdx.x >> 1, cb = blockIdx.x & 1;
  __shared__ float xs[64][68];
  __shared__ float wl[64][68];
  const int tid = threadIdx.x;
  const int ty = tid >> 4, tx = tid & 15;
  float acc[4][4] = {};
  for (int kc = 0; kc < IN_DIM; kc += 64) {
    __syncthreads();
#pragma unroll
    for (int p = 0; p < 4; p++) {
      const int idx = p*256 + tid;
      const int r = idx >> 4, k4 = idx & 15;
      *(float4*)&xs[r][k4*4] = *(const float4*)(x + (size_t)(rb*64 + r)*IN_DIM + kc + k4*4);
      *(float4*)&wl[r][k4*4] = *(const float4*)(W + (size_t)(cb*64 + r)*IN_DIM + kc + k4*4);
    }
    __syncthreads();
#pragma unroll
    for (int k4 = 0; k4 < 16; k4++) {
      float4 xr[4], wr[4];
#pragma unroll
      for (int i = 0; i < 4; i++) {
        xr[i] = *(const float4*)&xs[ty + i*16][k4*4];
        wr[i] = *(const float4*)&wl[tx + i*16][k4*4];
      }
#pragma unroll
      for (int i = 0; i < 4; i++)
#pragma unroll
        for (int j = 0; j < 4; j++)
          acc[i][j] += xr[i].x*wr[j].x + xr[i].y*wr[j].y + xr[i].z*wr[j].z + xr[i].w*wr[j].w;
    }
  }
#pragma unroll
  for (int i = 0; i < 4; i++)
#pragma unroll
    for (int j = 0; j < 4; j++)
      H[(size_t)(rb*64 + ty + i*16)*FEAT + cb*64 + tx + j*16] = acc[i][j];
}

// ---------------------------------------------------------------- k_er
// er[j][h] = dot(x[j,:], vr[h,:])  fp32-exact path feeding exp()
__global__ void k_er(const float* __restrict__ x, const float* __restrict__ vr,
                     float* __restrict__ er) {
  const int wave = threadIdx.x >> 6, lane = threadIdx.x & 63;
  const int j = blockIdx.x*4 + wave;
  float4 xv = ((const float4*)(x + (size_t)j*IN_DIM))[lane];
  float4 a0 = ((const float4*)vr)[lane];
  float4 a1 = ((const float4*)(vr + IN_DIM))[lane];
  float s0 = xv.x*a0.x + xv.y*a0.y + xv.z*a0.z + xv.w*a0.w;
  float s1 = xv.x*a1.x + xv.y*a1.y + xv.z*a1.z + xv.w*a1.w;
#pragma unroll
  for (int off = 32; off > 0; off >>= 1) {
    s0 += __shfl_down(s0, off);
    s1 += __shfl_down(s1, off);
  }
  if (lane == 0) { er[j*2+0] = s0; er[j*2+1] = s1; }
}

// ---------------------------------------------------------------- k_pack
// Build fragment-ordered bf16 B: frag[kstep][n][lane][j8]  (kstep = 32 k-rows)
//   lane l holds B[k = kstep*32 + (l>>4)*8 + j][col = n*16 + (l&15)], j in 0..8
//   B[j][c] = exp(er[j][c>>6]) * H[j][c]  (c<128) ; exp(er[j][c-128]) (c=128,129); 0 pad
__global__ void k_pack(const float* __restrict__ H, const float* __restrict__ er,
                       unsigned short* __restrict__ frag) {
  const int oct = blockIdx.x;          // j-octet, 0..1023
  const int c = threadIdx.x;           // 0..191, active < 144
  if (c >= 144) return;
  const int j0 = oct * 8;
  const int kb = oct >> 2, sub = oct & 3;
  unsigned short v[8];
  if (c < FEAT) {
    const int h = c >> 6;
#pragma unroll
    for (int t = 0; t < 8; t++) {
      float w = __expf(er[(j0 + t)*2 + h]);
      v[t] = f2bf(w * H[(size_t)(j0 + t)*FEAT + c]);
    }
  } else if (c < FEAT + HEADS) {
    const int h = c - FEAT;
#pragma unroll
    for (int t = 0; t < 8; t++) v[t] = f2bf(__expf(er[(j0 + t)*2 + h]));
  } else {
#pragma unroll
    for (int t = 0; t < 8; t++) v[t] = 0;
  }
  uint4 o;
  o.x = (unsigned)v[0] | ((unsigned)v[1] << 16);
  o.y = (unsigned)v[2] | ((unsigned)v[3] << 16);
  o.z = (unsigned)v[4] | ((unsigned)v[5] << 16);
  o.w = (unsigned)v[6] | ((unsigned)v[7] << 16);
  uint4* dst = (uint4*)frag + ((size_t)(kb*NTILES + (c >> 4)))*64 + (sub*16 + (c & 15));
  *dst = o;
}

// ---------------------------------------------------------------- k_main
// accum[ks][8192][132] = adj[:, ks-slice] @ B[ks-slice, 144]  (bf16 MFMA, fp32 acc)
// Barrier-free: no LDS, B fragments read straight from L1/L2, A double-buffered
// in registers. Grid 512 = 64 M-blocks (128 rows) x 8 K-splits. 4 waves/block,
// each wave: 32 rows x 144 cols. Plain stores to per-split slice (no atomics).
__global__ __launch_bounds__(256, 2) void k_main(const int* __restrict__ adj,
                                                 const uint4* __restrict__ fragB,
                                                 float* __restrict__ accum) {
  const int mb = blockIdx.x >> 3;         // 0..63
  const int ks = blockIdx.x & 7;          // 0..7
  const int tid = threadIdx.x;
  const int wave = tid >> 6, lane = tid & 63;
  const int m16 = lane & 15, quad = lane >> 4;

  const int row0 = mb*128 + wave*32 + m16;
  const int* a0 = adj + (size_t)row0*N_NODES + ks*1024 + quad*8;
  const int* a1 = a0 + (size_t)16*N_NODES;
  const uint4* bb = fragB + (size_t)(ks*32)*NTILES*64 + lane;

  f32x4 acc0[NTILES], acc1[NTILES];
#pragma unroll
  for (int n = 0; n < NTILES; n++) {
    acc0[n] = (f32x4){0.f, 0.f, 0.f, 0.f};
    acc1[n] = (f32x4){0.f, 0.f, 0.f, 0.f};
  }

  i32x4  Abuf[2][4];
  uu32x4 Bbuf[2][NTILES];

  auto loadA = [&](int kk, int buf) {
    const i32x4* p0 = (const i32x4*)(a0 + kk*32);
    const i32x4* p1 = (const i32x4*)(a1 + kk*32);
    Abuf[buf][0] = __builtin_nontemporal_load(p0);
    Abuf[buf][1] = __builtin_nontemporal_load(p0 + 1);
    Abuf[buf][2] = __builtin_nontemporal_load(p1);
    Abuf[buf][3] = __builtin_nontemporal_load(p1 + 1);
  };
  auto loadB = [&](int kk, int buf) {
    const uu32x4* b = (const uu32x4*)bb;
#pragma unroll
    for (int t = 0; t < NTILES; t++)
      Bbuf[buf][t] = b[(size_t)(kk*NTILES + t)*64];
  };
  auto conv = [&](const i32x4* A) -> bf16x8 {
    const int* ai = (const int*)A;
    unsigned u0 = (ai[0] ? 0x3F80u : 0u) | (ai[1] ? 0x3F800000u : 0u);
    unsigned u1 = (ai[2] ? 0x3F80u : 0u) | (ai[3] ? 0x3F800000u : 0u);
    unsigned u2 = (ai[4] ? 0x3F80u : 0u) | (ai[5] ? 0x3F800000u : 0u);
    unsigned u3 = (ai[6] ? 0x3F80u : 0u) | (ai[7] ? 0x3F800000u : 0u);
    uu32x4 u = {u0, u1, u2, u3};
    return __builtin_bit_cast(bf16x8, u);
  };
  auto compute = [&](int buf) {
    bf16x8 af0 = conv(&Abuf[buf][0]);
    bf16x8 af1 = conv(&Abuf[buf][2]);
#pragma unroll
    for (int n = 0; n < NTILES; n++) {
      bf16x8 bfr = __builtin_bit_cast(bf16x8, Bbuf[buf][n]);
      acc0[n] = __builtin_amdgcn_mfma_f32_16x16x32_bf16(af0, bfr, acc0[n], 0, 0, 0);
    }
#pragma unroll
    for (int n = 0; n < NTILES; n++) {
      bf16x8 bfr = __builtin_bit_cast(bf16x8, Bbuf[buf][n]);
      acc1[n] = __builtin_amdgcn_mfma_f32_16x16x32_bf16(af1, bfr, acc1[n], 0, 0, 0);
    }
  };

  loadA(0, 0); loadB(0, 0);
  for (int kk = 0; kk < 32; kk += 2) {
    loadA(kk + 1, 1); loadB(kk + 1, 1);
    compute(0);
    const int k2 = (kk + 2 < 32) ? kk + 2 : 31;   // clamp: redundant safe reload at tail
    loadA(k2, 0); loadB(k2, 0);
    compute(1);
  }

  // epilogue: C/D layout col=lane&15, row=quad*4+reg. Plain stores, full coverage.
  const int rb0 = mb*128 + wave*32 + quad*4;
  float* op = accum + (size_t)ks*N_NODES*ACC_STRIDE;
#pragma unroll
  for (int n = 0; n < NTILES; n++) {
    if (n == 8 && m16 >= HEADS) continue;  // cols 130..143 are padding
#pragma unroll
    for (int r = 0; r < 4; r++) {
      op[(size_t)(rb0 + r)*ACC_STRIDE + n*16 + m16]      = acc0[n][r];
      op[(size_t)(rb0 + 16 + r)*ACC_STRIDE + n*16 + m16] = acc1[n][r];
    }
  }
}

// ---------------------------------------------------------------- k_div
// out[i][c] = (sum_ks num) / (sum_ks den)
__global__ void k_div(const float* __restrict__ acc, float* __restrict__ out) {
  const int i = blockIdx.x, c = threadIdx.x;   // 8192 x 128
  const int h = c >> 6;
  float num = 0.f, den = 0.f;
#pragma unroll
  for (int s = 0; s < KSPLIT; s++) {
    const float* p = acc + ((size_t)s*N_NODES + i)*ACC_STRIDE;
    num += p[c];
    den += p[FEAT + h];
  }
  out[(size_t)i*FEAT + c] = num / den;
}

// ---------------------------------------------------------------- launch
extern "C" void kernel_launch(void* const* d_in, const int* in_sizes, int n_in,
                              void* d_out, int out_size, void* d_ws, size_t ws_size,
                              hipStream_t stream) {
  const float* x      = (const float*)d_in[0];
  const int*   adj    = (const int*)  d_in[1];
  const float* W      = (const float*)d_in[2];
  // d_in[3] = attn_l: cancels in softmax over j — unused.
  const float* attn_r = (const float*)d_in[4];

  char* ws = (char*)d_ws;
  float* vr            = (float*)(ws + 0);                 // 2 KB
  float* er            = (float*)(ws + 4096);              // 64 KB
  float* H             = (float*)(ws + 131072);            // 4 MB
  unsigned short* frag = (unsigned short*)(ws + 4325376);  // 2.25 MB
  float* acc           = (float*)(ws + 6684672);           // 8 x 4.33 MB
  float* out           = (float*)d_out;

  hipLaunchKernelGGL(k_vr,   dim3(1),    dim3(512), 0, stream, W, attn_r, vr);
  hipLaunchKernelGGL(k_h,    dim3(256),  dim3(256), 0, stream, x, W, H);
  hipLaunchKernelGGL(k_er,   dim3(2048), dim3(256), 0, stream, x, vr, er);
  hipLaunchKernelGGL(k_pack, dim3(1024), dim3(192), 0, stream, H, er, frag);
  hipLaunchKernelGGL(k_main, dim3(512),  dim3(256), 0, stream, adj, (const uint4*)frag, acc);
  hipLaunchKernelGGL(k_div,  dim3(8192), dim3(128), 0, stream, acc, out);
}